// Round 1
// baseline (34037.659 us; speedup 1.0000x reference)
//
#include <hip/hip_runtime.h>

// KoopmanLQR: backward Riccati recursion (255 steps) + batched gain GEMM.
// Round 0: correctness-first multi-launch fp32 implementation.
// K=256 (latent), U=64 (action), BATCH=131072.

#define KD 256
#define UD 64
#define NB 131072

// ---------------- init: qdiag=exp(ql), rdiag=exp(rl), qg=Q*g_goal, V0=diag(q), v0=qg
__global__ void k_init(const float* __restrict__ ql, const float* __restrict__ rl,
                       const float* __restrict__ gg,
                       float* __restrict__ V0, float* __restrict__ v0,
                       float* __restrict__ qdiag, float* __restrict__ rdiag,
                       float* __restrict__ qg) {
    int idx = blockIdx.x * 256 + threadIdx.x;
    if (idx < KD * KD) {
        int i = idx >> 8, j = idx & 255;
        V0[idx] = (i == j) ? expf(ql[i]) : 0.0f;
    }
    if (idx < KD) {
        float q = expf(ql[idx]);
        qdiag[idx] = q;
        float g = q * gg[idx];
        qg[idx] = g;
        v0[idx] = g;
    }
    if (idx < UD) rdiag[idx] = expf(rl[idx]);
}

// ---------------- stage A: AtV = A^T V, BtV = B^T V, atv = A^T v, btv = B^T v
__global__ void k_stageA(const float* __restrict__ A, const float* __restrict__ B,
                         const float* __restrict__ V, const float* __restrict__ v,
                         float* __restrict__ AtV, float* __restrict__ BtV,
                         float* __restrict__ atv, float* __restrict__ btv) {
    int idx = blockIdx.x * 256 + threadIdx.x;
    if (idx < 65536) {
        int i = idx >> 8, q = idx & 255;
        float acc = 0.0f;
        for (int p = 0; p < 256; ++p) acc += A[p * 256 + i] * V[p * 256 + q];
        AtV[idx] = acc;
    } else if (idx < 81920) {
        int t = idx - 65536;
        int i = t >> 8, q = t & 255;
        float acc = 0.0f;
        for (int p = 0; p < 256; ++p) acc += B[p * 64 + i] * V[p * 256 + q];
        BtV[t] = acc;
    } else if (idx < 82176) {
        int i = idx - 81920;
        float acc = 0.0f;
        for (int p = 0; p < 256; ++p) acc += A[p * 256 + i] * v[p];
        atv[i] = acc;
    } else if (idx < 82240) {
        int i = idx - 82176;
        float acc = 0.0f;
        for (int p = 0; p < 256; ++p) acc += B[p * 64 + i] * v[p];
        btv[i] = acc;
    }
}

// ---------------- stage B: AtVA = AtV*A, S = BtV*A, Vuu = BtV*B + diag(r)
__global__ void k_stageB(const float* __restrict__ A, const float* __restrict__ B,
                         const float* __restrict__ rdiag,
                         const float* __restrict__ AtV, const float* __restrict__ BtV,
                         float* __restrict__ AtVA, float* __restrict__ S,
                         float* __restrict__ Vuu) {
    int idx = blockIdx.x * 256 + threadIdx.x;
    if (idx < 65536) {
        int i = idx >> 8, q = idx & 255;
        float acc = 0.0f;
        for (int p = 0; p < 256; ++p) acc += AtV[i * 256 + p] * A[p * 256 + q];
        AtVA[idx] = acc;
    } else if (idx < 81920) {
        int t = idx - 65536;
        int i = t >> 8, q = t & 255;
        float acc = 0.0f;
        for (int p = 0; p < 256; ++p) acc += BtV[i * 256 + p] * A[p * 256 + q];
        S[t] = acc;
    } else if (idx < 86016) {
        int t = idx - 81920;
        int i = t >> 6, j = t & 63;
        float acc = (i == j) ? rdiag[i] : 0.0f;
        for (int p = 0; p < 256; ++p) acc += BtV[i * 256 + p] * B[p * 64 + j];
        Vuu[t] = acc;
    }
}

// ---------------- 64x64 Cholesky (single workgroup), writes lower-tri L (upper zeroed)
__global__ void k_chol(const float* __restrict__ Vuu, float* __restrict__ L) {
    __shared__ float M[64 * 64];
    int tid = threadIdx.x;
    for (int e = tid; e < 4096; e += 256) M[e] = Vuu[e];
    __syncthreads();
    int i = tid & 63, c = tid >> 6;  // c in 0..3
    for (int j = 0; j < 64; ++j) {
        if (tid == 0) M[j * 64 + j] = sqrtf(M[j * 64 + j]);
        __syncthreads();
        float d = M[j * 64 + j];
        if (c == 0 && i > j) M[i * 64 + j] /= d;
        __syncthreads();
        if (i > j) {
            float lij = M[i * 64 + j];
            for (int k = j + 1 + c; k <= i; k += 4)
                M[i * 64 + k] -= lij * M[k * 64 + j];
        }
        __syncthreads();
    }
    for (int e = tid; e < 4096; e += 256) {
        int r = e >> 6, k = e & 63;
        L[e] = (k <= r) ? M[e] : 0.0f;
    }
}

// ---------------- forward solve: X = L^-1 S (257 columns incl. btv -> y), wave per column
__global__ void k_solve_fwd(const float* __restrict__ L, const float* __restrict__ S,
                            const float* __restrict__ btv,
                            float* __restrict__ X, float* __restrict__ yv) {
    int w = (blockIdx.x * 256 + threadIdx.x) >> 6;
    int lane = threadIdx.x & 63;
    if (w >= 257) return;
    float x = (w < 256) ? S[lane * 256 + w] : btv[lane];
    for (int a = 0; a < 64; ++a) {
        float val = (lane < a) ? L[a * 64 + lane] * x : 0.0f;
        for (int o = 32; o > 0; o >>= 1) val += __shfl_xor(val, o, 64);
        float xa = (__shfl(x, a, 64) - val) / L[a * 64 + a];
        if (lane == a) x = xa;
    }
    if (w < 256) X[lane * 256 + w] = x;
    else yv[lane] = x;
}

// ---------------- full solve (fwd+bwd): K0 = Vuu^-1 S, k0 = Vuu^-1 btv
__global__ void k_solveK(const float* __restrict__ L, const float* __restrict__ S,
                         const float* __restrict__ btv,
                         float* __restrict__ K0, float* __restrict__ k0) {
    int w = (blockIdx.x * 256 + threadIdx.x) >> 6;
    int lane = threadIdx.x & 63;
    if (w >= 257) return;
    float x = (w < 256) ? S[lane * 256 + w] : btv[lane];
    for (int a = 0; a < 64; ++a) {
        float val = (lane < a) ? L[a * 64 + lane] * x : 0.0f;
        for (int o = 32; o > 0; o >>= 1) val += __shfl_xor(val, o, 64);
        float xa = (__shfl(x, a, 64) - val) / L[a * 64 + a];
        if (lane == a) x = xa;
    }
    for (int a = 63; a >= 0; --a) {
        float val = (lane > a) ? L[lane * 64 + a] * x : 0.0f;
        for (int o = 32; o > 0; o >>= 1) val += __shfl_xor(val, o, 64);
        float xa = (__shfl(x, a, 64) - val) / L[a * 64 + a];
        if (lane == a) x = xa;
    }
    if (w < 256) K0[lane * 256 + w] = x;
    else k0[lane] = x;
}

// ---------------- stage D: Vn = Q + AtVA - X^T X ; vn = atv + qg - X^T y
__global__ void k_stageD(const float* __restrict__ qdiag, const float* __restrict__ qg,
                         const float* __restrict__ AtVA, const float* __restrict__ X,
                         const float* __restrict__ atv, const float* __restrict__ yv,
                         float* __restrict__ Vn, float* __restrict__ vn) {
    int idx = blockIdx.x * 256 + threadIdx.x;
    if (idx < 65536) {
        int i = idx >> 8, q = idx & 255;
        float acc = AtVA[idx];
        for (int a = 0; a < 64; ++a) acc -= X[a * 256 + i] * X[a * 256 + q];
        Vn[idx] = acc + ((i == q) ? qdiag[i] : 0.0f);
    } else if (idx < 65792) {
        int i = idx - 65536;
        float acc = atv[i] + qg[i];
        for (int a = 0; a < 64; ++a) acc -= X[a * 256 + i] * yv[a];
        vn[i] = acc;
    }
}

// ---------------- final: out[b][j] = clip(k0[j] - sum_k g0[b][k]*K0[j][k], -1, 1)
__global__ __launch_bounds__(256) void k_gemm(const float* __restrict__ g0,
                                              const float* __restrict__ K0,
                                              const float* __restrict__ k0,
                                              float* __restrict__ out) {
    __shared__ __align__(16) float g0t[64 * 68];  // [k_local][row] transposed tile
    __shared__ __align__(16) float kt[64 * 68];   // [k_local][j]
    int tid = threadIdx.x;
    int base = blockIdx.x * 64;
    int tb = tid >> 4;   // 0..15 -> rows 4*tb..4*tb+3
    int tj = tid & 15;   // 0..15 -> cols 4*tj..4*tj+3
    float acc[4][4] = {{0.f}};
    for (int kc = 0; kc < 4; ++kc) {
        __syncthreads();
        for (int e = tid; e < 4096; e += 256) {
            int r = e >> 6, kl = e & 63;
            g0t[kl * 68 + r] = g0[(base + r) * 256 + kc * 64 + kl];
        }
        for (int e = tid; e < 4096; e += 256) {
            int j = e >> 6, kl = e & 63;
            kt[kl * 68 + j] = K0[j * 256 + kc * 64 + kl];
        }
        __syncthreads();
        for (int kl = 0; kl < 64; ++kl) {
            float4 g = *(const float4*)&g0t[kl * 68 + 4 * tb];
            float4 kv = *(const float4*)&kt[kl * 68 + 4 * tj];
            acc[0][0] += g.x * kv.x; acc[0][1] += g.x * kv.y; acc[0][2] += g.x * kv.z; acc[0][3] += g.x * kv.w;
            acc[1][0] += g.y * kv.x; acc[1][1] += g.y * kv.y; acc[1][2] += g.y * kv.z; acc[1][3] += g.y * kv.w;
            acc[2][0] += g.z * kv.x; acc[2][1] += g.z * kv.y; acc[2][2] += g.z * kv.z; acc[2][3] += g.z * kv.w;
            acc[3][0] += g.w * kv.x; acc[3][1] += g.w * kv.y; acc[3][2] += g.w * kv.z; acc[3][3] += g.w * kv.w;
        }
    }
    float c0 = k0[4 * tj + 0], c1 = k0[4 * tj + 1], c2 = k0[4 * tj + 2], c3 = k0[4 * tj + 3];
    for (int i = 0; i < 4; ++i) {
        float4 o;
        o.x = fminf(1.0f, fmaxf(-1.0f, c0 - acc[i][0]));
        o.y = fminf(1.0f, fmaxf(-1.0f, c1 - acc[i][1]));
        o.z = fminf(1.0f, fmaxf(-1.0f, c2 - acc[i][2]));
        o.w = fminf(1.0f, fmaxf(-1.0f, c3 - acc[i][3]));
        *(float4*)&out[(base + 4 * tb + i) * 64 + 4 * tj] = o;
    }
}

extern "C" void kernel_launch(void* const* d_in, const int* in_sizes, int n_in,
                              void* d_out, int out_size, void* d_ws, size_t ws_size,
                              hipStream_t stream) {
    const float* g0 = (const float*)d_in[0];
    const float* A  = (const float*)d_in[1];
    const float* B  = (const float*)d_in[2];
    const float* ql = (const float*)d_in[3];
    const float* rl = (const float*)d_in[4];
    const float* gg = (const float*)d_in[5];
    // d_in[6] = T (==256), hardcoded.

    float* ws = (float*)d_ws;
    float* V0   = ws;               // 65536
    float* V1   = V0 + 65536;       // 65536
    float* AtV  = V1 + 65536;       // 65536
    float* AtVA = AtV + 65536;      // 65536
    float* BtV  = AtVA + 65536;     // 16384
    float* S    = BtV + 16384;      // 16384
    float* X    = S + 16384;        // 16384
    float* K0   = X + 16384;        // 16384
    float* L    = K0 + 16384;       // 4096
    float* Vuu  = L + 4096;         // 4096
    float* qdiag = Vuu + 4096;      // 256
    float* rdiag = qdiag + 256;     // 64 (padded 256)
    float* qg   = rdiag + 256;      // 256
    float* v0   = qg + 256;         // 256
    float* v1   = v0 + 256;         // 256
    float* atv  = v1 + 256;         // 256
    float* btv  = atv + 256;        // 64 (padded 256)
    float* yv   = btv + 256;        // 64 (padded 256)
    float* k0   = yv + 256;         // 64
    // total ~338k floats = 1.36 MB of workspace

    k_init<<<256, 256, 0, stream>>>(ql, rl, gg, V0, v0, qdiag, rdiag, qg);

    float* Vc = V0; float* Vn = V1;
    float* vc = v0; float* vn = v1;
    // reference scan: 256 iterations; last emitted gains use V after 255 updates
    for (int t = 0; t < 255; ++t) {
        k_stageA<<<322, 256, 0, stream>>>(A, B, Vc, vc, AtV, BtV, atv, btv);
        k_stageB<<<336, 256, 0, stream>>>(A, B, rdiag, AtV, BtV, AtVA, S, Vuu);
        k_chol<<<1, 256, 0, stream>>>(Vuu, L);
        k_solve_fwd<<<65, 256, 0, stream>>>(L, S, btv, X, yv);
        k_stageD<<<258, 256, 0, stream>>>(qdiag, qg, AtVA, X, atv, yv, Vn, vn);
        float* tmp = Vc; Vc = Vn; Vn = tmp;
        float* tv = vc; vc = vn; vn = tv;
    }
    // gain extraction from V_255, v_255
    k_stageA<<<322, 256, 0, stream>>>(A, B, Vc, vc, AtV, BtV, atv, btv);
    k_stageB<<<336, 256, 0, stream>>>(A, B, rdiag, AtV, BtV, AtVA, S, Vuu);
    k_chol<<<1, 256, 0, stream>>>(Vuu, L);
    k_solveK<<<65, 256, 0, stream>>>(L, S, btv, K0, k0);
    // final batched u = clip(-g0 @ K0^T + k0)
    k_gemm<<<NB / 64, 256, 0, stream>>>(g0, K0, k0, (float*)d_out);
}

// Round 2
// 21883.269 us; speedup vs baseline: 1.5554x; 1.5554x over previous
//
#include <hip/hip_runtime.h>

// KoopmanLQR via structured doubling (SDA): 8 iterations replace 255 Riccati steps.
// H_k = X_{2^k} (X_1 = Q)  =>  H_8 = V after 255 updates. Affine terms (a_k, h_k)
// derived from block-partitioned augmented SDA: h_8 = v_255 exactly.
// K=256, U=64, BATCH=131072. All fp32.

#define KD 256
#define UD 64
#define NB 131072

// ======================= generic 64x64-tile matmul helper =======================
// C[bi,bj] = op(A)*op(B) (+C0) (+I). All matrices 256x256 row-major ld=256.
__device__ __forceinline__ void mm_tile(const float* __restrict__ Aop,
                                        const float* __restrict__ Bop,
                                        const float* __restrict__ C0,
                                        float* __restrict__ C,
                                        int tra, int trb, int addI, int bi, int bj) {
    __shared__ __align__(16) float At[64 * 68];
    __shared__ __align__(16) float Bt[64 * 68];
    int tid = threadIdx.x;
    int tb = tid >> 4, tj = tid & 15;
    float acc[4][4] = {{0.f}};
    for (int kc = 0; kc < 4; ++kc) {
        __syncthreads();
        if (!tra) {
            for (int e = tid; e < 4096; e += 256) {
                int r = e >> 6, c = e & 63;
                At[c * 68 + r] = Aop[(bi * 64 + r) * 256 + kc * 64 + c];
            }
        } else {  // op(A)[i][k] = A[k][i]
            for (int e = tid; e < 4096; e += 256) {
                int r = e & 63, c = e >> 6;
                At[c * 68 + r] = Aop[(kc * 64 + c) * 256 + bi * 64 + r];
            }
        }
        if (!trb) {
            for (int e = tid; e < 4096; e += 256) {
                int j2 = e & 63, c = e >> 6;
                Bt[c * 68 + j2] = Bop[(kc * 64 + c) * 256 + bj * 64 + j2];
            }
        } else {  // op(B)[k][j] = B[j][k]
            for (int e = tid; e < 4096; e += 256) {
                int j2 = e >> 6, c = e & 63;
                Bt[c * 68 + j2] = Bop[(bj * 64 + j2) * 256 + kc * 64 + c];
            }
        }
        __syncthreads();
        for (int kl = 0; kl < 64; ++kl) {
            float4 a4 = *(const float4*)&At[kl * 68 + 4 * tb];
            float4 b4 = *(const float4*)&Bt[kl * 68 + 4 * tj];
            acc[0][0] += a4.x * b4.x; acc[0][1] += a4.x * b4.y; acc[0][2] += a4.x * b4.z; acc[0][3] += a4.x * b4.w;
            acc[1][0] += a4.y * b4.x; acc[1][1] += a4.y * b4.y; acc[1][2] += a4.y * b4.z; acc[1][3] += a4.y * b4.w;
            acc[2][0] += a4.z * b4.x; acc[2][1] += a4.z * b4.y; acc[2][2] += a4.z * b4.z; acc[2][3] += a4.z * b4.w;
            acc[3][0] += a4.w * b4.x; acc[3][1] += a4.w * b4.y; acc[3][2] += a4.w * b4.z; acc[3][3] += a4.w * b4.w;
        }
    }
    for (int ii = 0; ii < 4; ++ii)
        for (int jj = 0; jj < 4; ++jj) {
            int gi = bi * 64 + 4 * tb + ii, gj = bj * 64 + 4 * tj + jj;
            float vv = acc[ii][jj];
            if (C0) vv += C0[gi * 256 + gj];
            if (addI && gi == gj) vv += 1.f;
            C[gi * 256 + gj] = vv;
        }
}

// ======================= init =======================
__global__ void k_init(const float* __restrict__ ql, const float* __restrict__ rl,
                       const float* __restrict__ gg, const float* __restrict__ A,
                       float* __restrict__ H, float* __restrict__ F,
                       float* __restrict__ a, float* __restrict__ h,
                       float* __restrict__ rinv) {
    int idx = blockIdx.x * 256 + threadIdx.x;  // grid 256 -> 65536
    int i = idx >> 8, j = idx & 255;
    H[idx] = (i == j) ? expf(ql[i]) : 0.f;
    F[idx] = A[idx];
    if (idx < 256) { h[idx] = expf(ql[idx]) * gg[idx]; a[idx] = 0.f; }
    if (idx < 64) rinv[idx] = expf(-rl[idx]);
}

// G = B R^-1 B^T : block per row
__global__ void k_initG(const float* __restrict__ B, const float* __restrict__ rinv,
                        float* __restrict__ G) {
    __shared__ float bi[64];
    int i = blockIdx.x, tid = threadIdx.x;
    if (tid < 64) bi[tid] = B[i * 64 + tid] * rinv[tid];
    __syncthreads();
    float acc = 0.f;
    for (int u = 0; u < 64; ++u) acc += bi[u] * B[tid * 64 + u];
    G[i * 256 + tid] = acc;
}

// ======================= M = I + G*H ; t = a - G*h =======================
__global__ void k_formMt(const float* __restrict__ G, const float* __restrict__ H,
                         const float* __restrict__ a, const float* __restrict__ h,
                         float* __restrict__ M, float* __restrict__ t) {
    if (blockIdx.x < 16) {
        mm_tile(G, H, nullptr, M, 0, 0, 1, (int)blockIdx.x >> 2, (int)blockIdx.x & 3);
    } else {
        int i = threadIdx.x;
        float acc = a[i];
        for (int j = 0; j < 256; ++j) acc -= G[j * 256 + i] * h[j];  // G symmetric
        t[i] = acc;
    }
}

// ======================= blocked unpivoted LU of M (in place) =======================
__global__ void k_lu_panel(float* __restrict__ M, int p) {
    __shared__ float P[256 * 65];
    int tid = threadIdx.x;
    int nr = 256 - 64 * p;
    for (int e = tid; e < nr * 64; e += 256) {
        int r = e >> 6, c = e & 63;
        P[r * 65 + c] = M[(64 * p + r) * 256 + 64 * p + c];
    }
    __syncthreads();
    for (int j = 0; j < 64; ++j) {
        float piv = P[j * 65 + j];
        int i = tid;
        if (i > j && i < nr) {
            float l = P[i * 65 + j] / piv;
            P[i * 65 + j] = l;
            for (int c = j + 1; c < 64; ++c) P[i * 65 + c] -= l * P[j * 65 + c];
        }
        __syncthreads();
    }
    for (int e = tid; e < nr * 64; e += 256) {
        int r = e >> 6, c = e & 63;
        M[(64 * p + r) * 256 + 64 * p + c] = P[r * 65 + c];
    }
}

// U12 = L11^{-1} * M12 : one 64-thread WG per 64-col chunk; register forward solve
__global__ void k_lu_trsm(float* __restrict__ M, int p) {
    __shared__ float L11[64 * 65];
    int tid = threadIdx.x;  // 64
    for (int e = tid; e < 4096; e += 64) {
        int r = e >> 6, c = e & 63;
        L11[r * 65 + c] = M[(64 * p + r) * 256 + 64 * p + c];
    }
    __syncthreads();
    int gc = 64 * (p + 1) + blockIdx.x * 64 + tid;
    float u[64];
#pragma unroll
    for (int j = 0; j < 64; ++j) {
        float s = M[(64 * p + j) * 256 + gc];
#pragma unroll
        for (int q = 0; q < 64; ++q) if (q < j) s -= L11[j * 65 + q] * u[q];
        u[j] = s;
    }
#pragma unroll
    for (int j = 0; j < 64; ++j) M[(64 * p + j) * 256 + gc] = u[j];
}

// trailing update M22 -= L21 * U12
__global__ void k_lu_trail(float* __restrict__ M, int p) {
    __shared__ __align__(16) float At[64 * 68];
    __shared__ __align__(16) float Bt[64 * 68];
    int m64 = (192 - 64 * p) >> 6;
    int bi = blockIdx.x / m64, bj = blockIdx.x % m64;
    int r0 = 64 * (p + 1) + bi * 64, c0 = 64 * (p + 1) + bj * 64;
    int tid = threadIdx.x;
    int tb = tid >> 4, tj = tid & 15;
    for (int e = tid; e < 4096; e += 256) {
        int r = e >> 6, k = e & 63;
        At[k * 68 + r] = M[(r0 + r) * 256 + 64 * p + k];
    }
    for (int e = tid; e < 4096; e += 256) {
        int k = e >> 6, j2 = e & 63;
        Bt[k * 68 + j2] = M[(64 * p + k) * 256 + c0 + j2];
    }
    __syncthreads();
    float acc[4][4] = {{0.f}};
    for (int kl = 0; kl < 64; ++kl) {
        float4 a4 = *(const float4*)&At[kl * 68 + 4 * tb];
        float4 b4 = *(const float4*)&Bt[kl * 68 + 4 * tj];
        acc[0][0] += a4.x * b4.x; acc[0][1] += a4.x * b4.y; acc[0][2] += a4.x * b4.z; acc[0][3] += a4.x * b4.w;
        acc[1][0] += a4.y * b4.x; acc[1][1] += a4.y * b4.y; acc[1][2] += a4.y * b4.z; acc[1][3] += a4.y * b4.w;
        acc[2][0] += a4.z * b4.x; acc[2][1] += a4.z * b4.y; acc[2][2] += a4.z * b4.z; acc[2][3] += a4.z * b4.w;
        acc[3][0] += a4.w * b4.x; acc[3][1] += a4.w * b4.y; acc[3][2] += a4.w * b4.z; acc[3][3] += a4.w * b4.w;
    }
    for (int ii = 0; ii < 4; ++ii)
        for (int jj = 0; jj < 4; ++jj)
            M[(r0 + 4 * tb + ii) * 256 + c0 + 4 * tj + jj] -= acc[ii][jj];
}

// ======================= block triangular solves, 513 RHS = [F | G | t] ==========
// forward (L unit lower), block-row p. 64-thread WGs, thread = one RHS column.
__global__ void k_fsolve(const float* __restrict__ M, const float* __restrict__ F,
                         const float* __restrict__ G, const float* __restrict__ t,
                         float* __restrict__ XF, float* __restrict__ XG,
                         float* __restrict__ z, int p) {
    __shared__ float Lb[64 * 65];
    int tid = threadIdx.x;
    int w = blockIdx.x;  // 0..8
    const float* R; float* X; int c; int ld; int valid = 1;
    if (w < 4)      { R = F; X = XF; c = w * 64 + tid; ld = 256; }
    else if (w < 8) { R = G; X = XG; c = (w - 4) * 64 + tid; ld = 256; }
    else            { R = t; X = z;  c = 0; ld = 1; valid = (tid == 0); }
    float s[64];
#pragma unroll
    for (int i = 0; i < 64; ++i) s[i] = valid ? R[(64 * p + i) * ld + c] : 0.f;
    for (int q = 0; q < p; ++q) {
        __syncthreads();
        for (int e = tid; e < 4096; e += 64) {
            int r = e >> 6, cc = e & 63;
            Lb[r * 65 + cc] = M[(64 * p + r) * 256 + 64 * q + cc];
        }
        __syncthreads();
        for (int j = 0; j < 64; ++j) {
            float xv = valid ? X[(64 * q + j) * ld + c] : 0.f;
#pragma unroll
            for (int i = 0; i < 64; ++i) s[i] -= Lb[i * 65 + j] * xv;
        }
    }
    __syncthreads();
    for (int e = tid; e < 4096; e += 64) {
        int r = e >> 6, cc = e & 63;
        Lb[r * 65 + cc] = M[(64 * p + r) * 256 + 64 * p + cc];
    }
    __syncthreads();
#pragma unroll
    for (int j = 0; j < 64; ++j) {
        float xj = s[j];
#pragma unroll
        for (int i = 0; i < 64; ++i) if (i > j) s[i] -= Lb[i * 65 + j] * xj;
    }
    if (valid)
#pragma unroll
        for (int j = 0; j < 64; ++j) X[(64 * p + j) * ld + c] = s[j];
}

// backward (U incl diag), block-row p (launched p=3..0), in place on XF/XG/z
__global__ void k_bsolve(const float* __restrict__ M, float* __restrict__ XF,
                         float* __restrict__ XG, float* __restrict__ z, int p) {
    __shared__ float Ub[64 * 65];
    int tid = threadIdx.x;
    int w = blockIdx.x;
    float* X; int c; int ld; int valid = 1;
    if (w < 4)      { X = XF; c = w * 64 + tid; ld = 256; }
    else if (w < 8) { X = XG; c = (w - 4) * 64 + tid; ld = 256; }
    else            { X = z;  c = 0; ld = 1; valid = (tid == 0); }
    float s[64];
#pragma unroll
    for (int i = 0; i < 64; ++i) s[i] = valid ? X[(64 * p + i) * ld + c] : 0.f;
    for (int q = p + 1; q < 4; ++q) {
        __syncthreads();
        for (int e = tid; e < 4096; e += 64) {
            int r = e >> 6, cc = e & 63;
            Ub[r * 65 + cc] = M[(64 * p + r) * 256 + 64 * q + cc];
        }
        __syncthreads();
        for (int j = 0; j < 64; ++j) {
            float xv = valid ? X[(64 * q + j) * ld + c] : 0.f;
#pragma unroll
            for (int i = 0; i < 64; ++i) s[i] -= Ub[i * 65 + j] * xv;
        }
    }
    __syncthreads();
    for (int e = tid; e < 4096; e += 64) {
        int r = e >> 6, cc = e & 63;
        Ub[r * 65 + cc] = M[(64 * p + r) * 256 + 64 * p + cc];
    }
    __syncthreads();
#pragma unroll
    for (int jr = 0; jr < 64; ++jr) {
        int j = 63 - jr;
        float xj = s[j] / Ub[j * 65 + j];
        s[j] = xj;
#pragma unroll
        for (int i = 0; i < 64; ++i) if (i < j) s[i] -= Ub[i * 65 + j] * xj;
    }
    if (valid)
#pragma unroll
        for (int j = 0; j < 64; ++j) X[(64 * p + j) * ld + c] = s[j];
}

// ======================= SDA updates =======================
// d20: Fn = F*XF ; HXF = H*XF ; P = F*XG ; wv = h + H*z ; av = F*z
__global__ void k_upd1(const float* __restrict__ F, const float* __restrict__ H,
                       const float* __restrict__ XF, const float* __restrict__ XG,
                       const float* __restrict__ z, const float* __restrict__ h,
                       float* __restrict__ Fn, float* __restrict__ HXF,
                       float* __restrict__ P, float* __restrict__ wv,
                       float* __restrict__ av) {
    int b = blockIdx.x;
    if (b < 16)       mm_tile(F, XF, nullptr, Fn,  0, 0, 0, b >> 2, b & 3);
    else if (b < 32)  mm_tile(H, XF, nullptr, HXF, 0, 0, 0, (b - 16) >> 2, (b - 16) & 3);
    else if (b < 48)  mm_tile(F, XG, nullptr, P,   0, 0, 0, (b - 32) >> 2, (b - 32) & 3);
    else if (b == 48) {
        int i = threadIdx.x;
        float acc = h[i];
        for (int j = 0; j < 256; ++j) acc += H[j * 256 + i] * z[j];  // H symmetric
        wv[i] = acc;
    } else {
        int i = threadIdx.x;
        float acc = 0.f;
        for (int j = 0; j < 256; ++j) acc += F[i * 256 + j] * z[j];
        av[i] = acc;
    }
}

// d21: H += F^T*HXF ; G += P*F^T ; h += F^T*wv ; a += av
__global__ void k_upd2(const float* __restrict__ F, const float* __restrict__ HXF,
                       const float* __restrict__ P, const float* __restrict__ wv,
                       const float* __restrict__ av, float* __restrict__ H,
                       float* __restrict__ G, float* __restrict__ h,
                       float* __restrict__ a) {
    int b = blockIdx.x;
    if (b < 16)       mm_tile(F, HXF, H, H, 1, 0, 0, b >> 2, b & 3);
    else if (b < 32)  mm_tile(P, F,   G, G, 0, 1, 0, (b - 16) >> 2, (b - 16) & 3);
    else {
        int i = threadIdx.x;
        float acc = h[i];
        for (int pp = 0; pp < 256; ++pp) acc += F[pp * 256 + i] * wv[pp];
        h[i] = acc;
        a[i] += av[i];
    }
}

// ======================= final gains =======================
__global__ void k_btv(const float* __restrict__ B, const float* __restrict__ V,
                      const float* __restrict__ v, float* __restrict__ BtV,
                      float* __restrict__ btv) {
    if (blockIdx.x < 64) {
        int idx = blockIdx.x * 256 + threadIdx.x;
        int i = idx >> 8, q = idx & 255;
        float acc = 0.f;
        for (int p2 = 0; p2 < 256; ++p2) acc += B[p2 * 64 + i] * V[p2 * 256 + q];
        BtV[idx] = acc;
    } else if (threadIdx.x < 64) {
        int i = threadIdx.x;
        float acc = 0.f;
        for (int p2 = 0; p2 < 256; ++p2) acc += B[p2 * 64 + i] * v[p2];
        btv[i] = acc;
    }
}

__global__ void k_SVuu(const float* __restrict__ A, const float* __restrict__ B,
                       const float* __restrict__ rl, const float* __restrict__ BtV,
                       float* __restrict__ S, float* __restrict__ Vuu) {
    int bx = blockIdx.x;
    if (bx < 64) {
        int idx = bx * 256 + threadIdx.x;
        int i = idx >> 8, q = idx & 255;
        float acc = 0.f;
        for (int p2 = 0; p2 < 256; ++p2) acc += BtV[i * 256 + p2] * A[p2 * 256 + q];
        S[idx] = acc;
    } else {
        int tdx = (bx - 64) * 256 + threadIdx.x;
        int i = tdx >> 6, j = tdx & 63;
        float acc = (i == j) ? expf(rl[i]) : 0.f;
        for (int p2 = 0; p2 < 256; ++p2) acc += BtV[i * 256 + p2] * B[p2 * 64 + j];
        Vuu[tdx] = acc;
    }
}

// 64x64 SPD Cholesky, 1 WG
__global__ void k_chol(const float* __restrict__ Vuu, float* __restrict__ L) {
    __shared__ float Msh[64 * 64];
    int tid = threadIdx.x;
    for (int e = tid; e < 4096; e += 256) Msh[e] = Vuu[e];
    __syncthreads();
    int i = tid & 63, c = tid >> 6;
    for (int j = 0; j < 64; ++j) {
        if (tid == 0) Msh[j * 64 + j] = sqrtf(Msh[j * 64 + j]);
        __syncthreads();
        float d = Msh[j * 64 + j];
        if (c == 0 && i > j) Msh[i * 64 + j] /= d;
        __syncthreads();
        if (i > j) {
            float lij = Msh[i * 64 + j];
            for (int k = j + 1 + c; k <= i; k += 4)
                Msh[i * 64 + k] -= lij * Msh[k * 64 + j];
        }
        __syncthreads();
    }
    for (int e = tid; e < 4096; e += 256) {
        int r = e >> 6, k = e & 63;
        L[e] = (k <= r) ? Msh[e] : 0.f;
    }
}

// K0 = Vuu^-1 S, k0 = Vuu^-1 btv (fwd+bwd via wave shuffles)
__global__ void k_solveK(const float* __restrict__ L, const float* __restrict__ S,
                         const float* __restrict__ btv,
                         float* __restrict__ K0, float* __restrict__ k0) {
    int w = (blockIdx.x * 256 + threadIdx.x) >> 6;
    int lane = threadIdx.x & 63;
    if (w >= 257) return;
    float x = (w < 256) ? S[lane * 256 + w] : btv[lane];
    for (int a = 0; a < 64; ++a) {
        float val = (lane < a) ? L[a * 64 + lane] * x : 0.f;
        for (int o = 32; o > 0; o >>= 1) val += __shfl_xor(val, o, 64);
        float xa = (__shfl(x, a, 64) - val) / L[a * 64 + a];
        if (lane == a) x = xa;
    }
    for (int a = 63; a >= 0; --a) {
        float val = (lane > a) ? L[lane * 64 + a] * x : 0.f;
        for (int o = 32; o > 0; o >>= 1) val += __shfl_xor(val, o, 64);
        float xa = (__shfl(x, a, 64) - val) / L[a * 64 + a];
        if (lane == a) x = xa;
    }
    if (w < 256) K0[lane * 256 + w] = x;
    else k0[lane] = x;
}

// u = clip(-g0 @ K0^T + k0)
__global__ __launch_bounds__(256) void k_gemm(const float* __restrict__ g0,
                                              const float* __restrict__ K0,
                                              const float* __restrict__ k0,
                                              float* __restrict__ out) {
    __shared__ __align__(16) float g0t[64 * 68];
    __shared__ __align__(16) float kt[64 * 68];
    int tid = threadIdx.x;
    int base = blockIdx.x * 64;
    int tb = tid >> 4;
    int tj = tid & 15;
    float acc[4][4] = {{0.f}};
    for (int kc = 0; kc < 4; ++kc) {
        __syncthreads();
        for (int e = tid; e < 4096; e += 256) {
            int r = e >> 6, kl = e & 63;
            g0t[kl * 68 + r] = g0[(base + r) * 256 + kc * 64 + kl];
        }
        for (int e = tid; e < 4096; e += 256) {
            int j = e >> 6, kl = e & 63;
            kt[kl * 68 + j] = K0[j * 256 + kc * 64 + kl];
        }
        __syncthreads();
        for (int kl = 0; kl < 64; ++kl) {
            float4 g = *(const float4*)&g0t[kl * 68 + 4 * tb];
            float4 kv = *(const float4*)&kt[kl * 68 + 4 * tj];
            acc[0][0] += g.x * kv.x; acc[0][1] += g.x * kv.y; acc[0][2] += g.x * kv.z; acc[0][3] += g.x * kv.w;
            acc[1][0] += g.y * kv.x; acc[1][1] += g.y * kv.y; acc[1][2] += g.y * kv.z; acc[1][3] += g.y * kv.w;
            acc[2][0] += g.z * kv.x; acc[2][1] += g.z * kv.y; acc[2][2] += g.z * kv.z; acc[2][3] += g.z * kv.w;
            acc[3][0] += g.w * kv.x; acc[3][1] += g.w * kv.y; acc[3][2] += g.w * kv.z; acc[3][3] += g.w * kv.w;
        }
    }
    float c0 = k0[4 * tj + 0], c1 = k0[4 * tj + 1], c2 = k0[4 * tj + 2], c3 = k0[4 * tj + 3];
    for (int i = 0; i < 4; ++i) {
        float4 o;
        o.x = fminf(1.0f, fmaxf(-1.0f, c0 - acc[i][0]));
        o.y = fminf(1.0f, fmaxf(-1.0f, c1 - acc[i][1]));
        o.z = fminf(1.0f, fmaxf(-1.0f, c2 - acc[i][2]));
        o.w = fminf(1.0f, fmaxf(-1.0f, c3 - acc[i][3]));
        *(float4*)&out[(base + 4 * tb + i) * 64 + 4 * tj] = o;
    }
}

extern "C" void kernel_launch(void* const* d_in, const int* in_sizes, int n_in,
                              void* d_out, int out_size, void* d_ws, size_t ws_size,
                              hipStream_t stream) {
    const float* g0 = (const float*)d_in[0];
    const float* A  = (const float*)d_in[1];
    const float* B  = (const float*)d_in[2];
    const float* ql = (const float*)d_in[3];
    const float* rl = (const float*)d_in[4];
    const float* gg = (const float*)d_in[5];
    // d_in[6] = T == 256, hardcoded (log2 T = 8 doublings).

    float* ws = (float*)d_ws;
    float* G   = ws;             // 65536
    float* H   = G   + 65536;
    float* F0  = H   + 65536;
    float* F1  = F0  + 65536;
    float* M   = F1  + 65536;
    float* XF  = M   + 65536;
    float* XG  = XF  + 65536;
    float* HXF = XG  + 65536;
    float* P   = HXF + 65536;
    float* BtV = P   + 65536;    // 16384
    float* S   = BtV + 16384;    // 16384
    float* K0  = S   + 16384;    // 16384
    float* Vuu = K0  + 16384;    // 4096
    float* L64 = Vuu + 4096;     // 4096
    float* a   = L64 + 4096;     // 256
    float* h   = a   + 256;      // 256
    float* t   = h   + 256;      // 256
    float* z   = t   + 256;      // 256
    float* wv  = z   + 256;      // 256
    float* av  = wv  + 256;      // 256
    float* rinv= av  + 256;      // 64
    float* btv = rinv+ 64;       // 64
    float* k0v = btv + 64;       // 64
    // total ~2.5 MB

    k_init<<<256, 256, 0, stream>>>(ql, rl, gg, A, H, F0, a, h, rinv);
    k_initG<<<256, 256, 0, stream>>>(B, rinv, G);

    float* Fc = F0; float* Fn = F1;
    for (int it = 0; it < 8; ++it) {
        k_formMt<<<17, 256, 0, stream>>>(G, H, a, h, M, t);
        for (int p = 0; p < 4; ++p) {
            k_lu_panel<<<1, 256, 0, stream>>>(M, p);
            if (p < 3) {
                k_lu_trsm<<<3 - p, 64, 0, stream>>>(M, p);
                k_lu_trail<<<(3 - p) * (3 - p), 256, 0, stream>>>(M, p);
            }
        }
        for (int p = 0; p < 4; ++p)
            k_fsolve<<<9, 64, 0, stream>>>(M, Fc, G, t, XF, XG, z, p);
        for (int p = 3; p >= 0; --p)
            k_bsolve<<<9, 64, 0, stream>>>(M, XF, XG, z, p);
        k_upd1<<<50, 256, 0, stream>>>(Fc, H, XF, XG, z, h, Fn, HXF, P, wv, av);
        k_upd2<<<33, 256, 0, stream>>>(Fc, HXF, P, wv, av, H, G, h, a);
        float* tmp = Fc; Fc = Fn; Fn = tmp;
    }

    // gains from V = H_8, v = h_8
    k_btv<<<65, 256, 0, stream>>>(B, H, h, BtV, btv);
    k_SVuu<<<80, 256, 0, stream>>>(A, B, rl, BtV, S, Vuu);
    k_chol<<<1, 256, 0, stream>>>(Vuu, L64);
    k_solveK<<<65, 256, 0, stream>>>(L64, S, btv, K0, k0v);
    k_gemm<<<NB / 64, 256, 0, stream>>>(g0, K0, k0v, (float*)d_out);
}

// Round 3
// 8854.911 us; speedup vs baseline: 3.8439x; 2.4713x over previous
//
#include <hip/hip_runtime.h>

// KoopmanLQR via structured doubling (SDA): 8 iterations replace 255 Riccati steps.
// Round 3: spill-free triangular solves. All triangular ops are GEMM-shaped with
// precomputed 64x64 diagonal-block inverses; fused 513-RHS solve in one launch.
// K=256, U=64, BATCH=131072. All fp32.

#define KD 256
#define UD 64
#define NB 131072

// ======================= generic 64x64-tile matmul helper =======================
// C[bi,bj] = op(A)*op(B) (+C0) (+I). All matrices 256x256 row-major ld=256.
__device__ __forceinline__ void mm_tile(const float* __restrict__ Aop,
                                        const float* __restrict__ Bop,
                                        const float* __restrict__ C0,
                                        float* __restrict__ C,
                                        int tra, int trb, int addI, int bi, int bj) {
    __shared__ __align__(16) float At[64 * 68];
    __shared__ __align__(16) float Bt[64 * 68];
    int tid = threadIdx.x;
    int tb = tid >> 4, tj = tid & 15;
    float acc[4][4] = {{0.f}};
    for (int kc = 0; kc < 4; ++kc) {
        __syncthreads();
        if (!tra) {
            for (int e = tid; e < 4096; e += 256) {
                int r = e >> 6, c = e & 63;
                At[c * 68 + r] = Aop[(bi * 64 + r) * 256 + kc * 64 + c];
            }
        } else {
            for (int e = tid; e < 4096; e += 256) {
                int r = e & 63, c = e >> 6;
                At[c * 68 + r] = Aop[(kc * 64 + c) * 256 + bi * 64 + r];
            }
        }
        if (!trb) {
            for (int e = tid; e < 4096; e += 256) {
                int j2 = e & 63, c = e >> 6;
                Bt[c * 68 + j2] = Bop[(kc * 64 + c) * 256 + bj * 64 + j2];
            }
        } else {
            for (int e = tid; e < 4096; e += 256) {
                int j2 = e >> 6, c = e & 63;
                Bt[c * 68 + j2] = Bop[(bj * 64 + j2) * 256 + kc * 64 + c];
            }
        }
        __syncthreads();
        for (int kl = 0; kl < 64; ++kl) {
            float4 a4 = *(const float4*)&At[kl * 68 + 4 * tb];
            float4 b4 = *(const float4*)&Bt[kl * 68 + 4 * tj];
            acc[0][0] += a4.x * b4.x; acc[0][1] += a4.x * b4.y; acc[0][2] += a4.x * b4.z; acc[0][3] += a4.x * b4.w;
            acc[1][0] += a4.y * b4.x; acc[1][1] += a4.y * b4.y; acc[1][2] += a4.y * b4.z; acc[1][3] += a4.y * b4.w;
            acc[2][0] += a4.z * b4.x; acc[2][1] += a4.z * b4.y; acc[2][2] += a4.z * b4.z; acc[2][3] += a4.z * b4.w;
            acc[3][0] += a4.w * b4.x; acc[3][1] += a4.w * b4.y; acc[3][2] += a4.w * b4.z; acc[3][3] += a4.w * b4.w;
        }
    }
    for (int ii = 0; ii < 4; ++ii)
        for (int jj = 0; jj < 4; ++jj) {
            int gi = bi * 64 + 4 * tb + ii, gj = bj * 64 + 4 * tj + jj;
            float vv = acc[ii][jj];
            if (C0) vv += C0[gi * 256 + gj];
            if (addI && gi == gj) vv += 1.f;
            C[gi * 256 + gj] = vv;
        }
}

// ======================= init =======================
__global__ void k_init(const float* __restrict__ ql, const float* __restrict__ rl,
                       const float* __restrict__ gg, const float* __restrict__ A,
                       float* __restrict__ H, float* __restrict__ F,
                       float* __restrict__ a, float* __restrict__ h,
                       float* __restrict__ rinv) {
    int idx = blockIdx.x * 256 + threadIdx.x;
    int i = idx >> 8, j = idx & 255;
    H[idx] = (i == j) ? expf(ql[i]) : 0.f;
    F[idx] = A[idx];
    if (idx < 256) { h[idx] = expf(ql[idx]) * gg[idx]; a[idx] = 0.f; }
    if (idx < 64) rinv[idx] = expf(-rl[idx]);
}

// G = B R^-1 B^T : block per row
__global__ void k_initG(const float* __restrict__ B, const float* __restrict__ rinv,
                        float* __restrict__ G) {
    __shared__ float bi[64];
    int i = blockIdx.x, tid = threadIdx.x;
    if (tid < 64) bi[tid] = B[i * 64 + tid] * rinv[tid];
    __syncthreads();
    float acc = 0.f;
    for (int u = 0; u < 64; ++u) acc += bi[u] * B[tid * 64 + u];
    G[i * 256 + tid] = acc;
}

// ======================= M = I + G*H ; t = a - G*h =======================
__global__ void k_formMt(const float* __restrict__ G, const float* __restrict__ H,
                         const float* __restrict__ a, const float* __restrict__ h,
                         float* __restrict__ M, float* __restrict__ t) {
    if (blockIdx.x < 16) {
        mm_tile(G, H, nullptr, M, 0, 0, 1, (int)blockIdx.x >> 2, (int)blockIdx.x & 3);
    } else {
        int i = threadIdx.x;
        float acc = a[i];
        for (int j = 0; j < 256; ++j) acc -= G[j * 256 + i] * h[j];  // G symmetric
        t[i] = acc;
    }
}

// ======================= LU panel + diagonal-block inverses =======================
// Factorizes the nr x 64 panel at (64p,64p) in place; then inverts the 64x64
// diagonal L (unit lower) and U (upper incl diag) blocks into Linv/Uinv.
__global__ void k_lu_panel(float* __restrict__ M, float* __restrict__ Linv,
                           float* __restrict__ Uinv, int p) {
    __shared__ float P[256 * 65];
    __shared__ float Xl[64 * 65];
    __shared__ float Xu[64 * 65];
    int tid = threadIdx.x;
    int nr = 256 - 64 * p;
    for (int e = tid; e < nr * 64; e += 256) {
        int r = e >> 6, c = e & 63;
        P[r * 65 + c] = M[(64 * p + r) * 256 + 64 * p + c];
    }
    __syncthreads();
    for (int j = 0; j < 64; ++j) {
        float piv = P[j * 65 + j];
        int i = tid;
        if (i > j && i < nr) {
            float l = P[i * 65 + j] / piv;
            P[i * 65 + j] = l;
            for (int c = j + 1; c < 64; ++c) P[i * 65 + c] -= l * P[j * 65 + c];
        }
        __syncthreads();
    }
    for (int e = tid; e < nr * 64; e += 256) {
        int r = e >> 6, c = e & 63;
        M[(64 * p + r) * 256 + 64 * p + c] = P[r * 65 + c];
    }
    // --- invert diagonal blocks (wave 0: Linv, wave 1: Uinv), P read-only now ---
    if (tid < 64) {
        int c = tid;  // column of Linv; unit-lower => no divide
        for (int i = 0; i < 64; ++i) {
            float s = (i == c) ? 1.f : 0.f;
            for (int k = c; k < i; ++k) s -= P[i * 65 + k] * Xl[k * 65 + c];
            Xl[i * 65 + c] = (i >= c) ? s : 0.f;
        }
    } else if (tid < 128) {
        int c = tid - 64;  // column of Uinv
        for (int i = 63; i >= 0; --i) {
            float s = (i == c) ? 1.f : 0.f;
            for (int k = i + 1; k <= c; ++k) s -= P[i * 65 + k] * Xu[k * 65 + c];
            Xu[i * 65 + c] = (i <= c) ? s / P[i * 65 + i] : 0.f;
        }
    }
    __syncthreads();
    for (int e = tid; e < 4096; e += 256) {
        int r = e >> 6, c = e & 63;
        Linv[p * 4096 + e] = Xl[r * 65 + c];
        Uinv[p * 4096 + e] = Xu[r * 65 + c];
    }
}

// U12 = Linv_pp * M12, in place. One block per 64-col chunk q = p+1+blockIdx.x.
__global__ __launch_bounds__(256) void k_trsm2(float* __restrict__ M,
                                               const float* __restrict__ Linv, int p) {
    __shared__ __align__(16) float Lt[64 * 68];
    __shared__ __align__(16) float Bt[64 * 68];
    int q = p + 1 + blockIdx.x;
    int tid = threadIdx.x;
    int tb = tid >> 4, tj = tid & 15;
    for (int e = tid; e < 4096; e += 256) {
        int r = e >> 6, c = e & 63;
        Lt[c * 68 + r] = Linv[p * 4096 + r * 64 + c];      // Lt[k][i] = Linv[i][k]
        Bt[c * 68 + r] = M[(64 * p + c) * 256 + 64 * q + r]; // wait: see below
    }
    __syncthreads();
    // Bt staged as Bt[k][j] = M[(64p+k)*256 + 64q + j]; restage correctly:
    __syncthreads();
    for (int e = tid; e < 4096; e += 256) {
        int k = e >> 6, j2 = e & 63;
        Bt[k * 68 + j2] = M[(64 * p + k) * 256 + 64 * q + j2];
    }
    __syncthreads();
    float acc[4][4] = {{0.f}};
    for (int kl = 0; kl < 64; ++kl) {
        float4 a4 = *(const float4*)&Lt[kl * 68 + 4 * tb];
        float4 b4 = *(const float4*)&Bt[kl * 68 + 4 * tj];
        acc[0][0] += a4.x * b4.x; acc[0][1] += a4.x * b4.y; acc[0][2] += a4.x * b4.z; acc[0][3] += a4.x * b4.w;
        acc[1][0] += a4.y * b4.x; acc[1][1] += a4.y * b4.y; acc[1][2] += a4.y * b4.z; acc[1][3] += a4.y * b4.w;
        acc[2][0] += a4.z * b4.x; acc[2][1] += a4.z * b4.y; acc[2][2] += a4.z * b4.z; acc[2][3] += a4.z * b4.w;
        acc[3][0] += a4.w * b4.x; acc[3][1] += a4.w * b4.y; acc[3][2] += a4.w * b4.z; acc[3][3] += a4.w * b4.w;
    }
    for (int ii = 0; ii < 4; ++ii)
        for (int jj = 0; jj < 4; ++jj)
            M[(64 * p + 4 * tb + ii) * 256 + 64 * q + 4 * tj + jj] = acc[ii][jj];
}

// trailing update M22 -= L21 * U12
__global__ __launch_bounds__(256) void k_lu_trail(float* __restrict__ M, int p) {
    __shared__ __align__(16) float At[64 * 68];
    __shared__ __align__(16) float Bt[64 * 68];
    int m64 = 3 - p;
    int bi = blockIdx.x / m64, bj = blockIdx.x % m64;
    int r0 = 64 * (p + 1) + bi * 64, c0 = 64 * (p + 1) + bj * 64;
    int tid = threadIdx.x;
    int tb = tid >> 4, tj = tid & 15;
    for (int e = tid; e < 4096; e += 256) {
        int r = e >> 6, k = e & 63;
        At[k * 68 + r] = M[(r0 + r) * 256 + 64 * p + k];
    }
    for (int e = tid; e < 4096; e += 256) {
        int k = e >> 6, j2 = e & 63;
        Bt[k * 68 + j2] = M[(64 * p + k) * 256 + c0 + j2];
    }
    __syncthreads();
    float acc[4][4] = {{0.f}};
    for (int kl = 0; kl < 64; ++kl) {
        float4 a4 = *(const float4*)&At[kl * 68 + 4 * tb];
        float4 b4 = *(const float4*)&Bt[kl * 68 + 4 * tj];
        acc[0][0] += a4.x * b4.x; acc[0][1] += a4.x * b4.y; acc[0][2] += a4.x * b4.z; acc[0][3] += a4.x * b4.w;
        acc[1][0] += a4.y * b4.x; acc[1][1] += a4.y * b4.y; acc[1][2] += a4.y * b4.z; acc[1][3] += a4.y * b4.w;
        acc[2][0] += a4.z * b4.x; acc[2][1] += a4.z * b4.y; acc[2][2] += a4.z * b4.z; acc[2][3] += a4.z * b4.w;
        acc[3][0] += a4.w * b4.x; acc[3][1] += a4.w * b4.y; acc[3][2] += a4.w * b4.z; acc[3][3] += a4.w * b4.w;
    }
    for (int ii = 0; ii < 4; ++ii)
        for (int jj = 0; jj < 4; ++jj)
            M[(r0 + 4 * tb + ii) * 256 + c0 + 4 * tj + jj] -= acc[ii][jj];
}

// ======================= fused 513-RHS forward+backward solve =======================
// Block w owns 64 RHS columns (w<4: F, w<8: G, w==8: t). Entirely self-contained:
// full 256-row forward (unit-L) then backward (U) substitution via LDS-tiled GEMM
// stages with precomputed diagonal-block inverses. No register arrays.
__global__ __launch_bounds__(256) void k_solve_all(
    const float* __restrict__ M, const float* __restrict__ Linv,
    const float* __restrict__ Uinv, const float* __restrict__ F,
    const float* __restrict__ G, const float* __restrict__ t,
    float* __restrict__ XF, float* __restrict__ XG, float* __restrict__ z) {
    __shared__ __align__(16) float Xs[256 * 68];
    __shared__ __align__(16) float Lt[64 * 68];
    int tid = threadIdx.x;
    int w = blockIdx.x;
    const float* R; float* X; int ld, cbase, ncol;
    if (w < 4)      { R = F; X = XF; ld = 256; cbase = w * 64; ncol = 64; }
    else if (w < 8) { R = G; X = XG; ld = 256; cbase = (w - 4) * 64; ncol = 64; }
    else            { R = t; X = z;  ld = 1;   cbase = 0; ncol = 1; }
    for (int e = tid; e < 256 * 64; e += 256) {
        int row = e >> 6, cc = e & 63;
        Xs[row * 68 + cc] = (cc < ncol) ? R[row * ld + cbase + cc] : 0.f;
    }
    int tb = tid >> 4, tj = tid & 15;
    // ---- forward: L (unit lower) ----
    for (int p = 0; p < 4; ++p) {
        float acc[4][4] = {{0.f}};
        for (int q = 0; q < p; ++q) {
            __syncthreads();
            for (int e = tid; e < 4096; e += 256) {
                int r = e >> 6, c = e & 63;
                Lt[c * 68 + r] = M[(64 * p + r) * 256 + 64 * q + c];  // Lt[k][i]=L_pq[i][k]
            }
            __syncthreads();
            for (int kl = 0; kl < 64; ++kl) {
                float4 a4 = *(const float4*)&Lt[kl * 68 + 4 * tb];
                float4 b4 = *(const float4*)&Xs[(64 * q + kl) * 68 + 4 * tj];
                acc[0][0] += a4.x * b4.x; acc[0][1] += a4.x * b4.y; acc[0][2] += a4.x * b4.z; acc[0][3] += a4.x * b4.w;
                acc[1][0] += a4.y * b4.x; acc[1][1] += a4.y * b4.y; acc[1][2] += a4.y * b4.z; acc[1][3] += a4.y * b4.w;
                acc[2][0] += a4.z * b4.x; acc[2][1] += a4.z * b4.y; acc[2][2] += a4.z * b4.z; acc[2][3] += a4.z * b4.w;
                acc[3][0] += a4.w * b4.x; acc[3][1] += a4.w * b4.y; acc[3][2] += a4.w * b4.z; acc[3][3] += a4.w * b4.w;
            }
        }
        __syncthreads();
        for (int ii = 0; ii < 4; ++ii)
            for (int jj = 0; jj < 4; ++jj)
                Xs[(64 * p + 4 * tb + ii) * 68 + 4 * tj + jj] -= acc[ii][jj];
        __syncthreads();
        for (int e = tid; e < 4096; e += 256) {
            int r = e >> 6, c = e & 63;
            Lt[c * 68 + r] = Linv[p * 4096 + r * 64 + c];
        }
        __syncthreads();
        float acc2[4][4] = {{0.f}};
        for (int kl = 0; kl < 64; ++kl) {
            float4 a4 = *(const float4*)&Lt[kl * 68 + 4 * tb];
            float4 b4 = *(const float4*)&Xs[(64 * p + kl) * 68 + 4 * tj];
            acc2[0][0] += a4.x * b4.x; acc2[0][1] += a4.x * b4.y; acc2[0][2] += a4.x * b4.z; acc2[0][3] += a4.x * b4.w;
            acc2[1][0] += a4.y * b4.x; acc2[1][1] += a4.y * b4.y; acc2[1][2] += a4.y * b4.z; acc2[1][3] += a4.y * b4.w;
            acc2[2][0] += a4.z * b4.x; acc2[2][1] += a4.z * b4.y; acc2[2][2] += a4.z * b4.z; acc2[2][3] += a4.z * b4.w;
            acc2[3][0] += a4.w * b4.x; acc2[3][1] += a4.w * b4.y; acc2[3][2] += a4.w * b4.z; acc2[3][3] += a4.w * b4.w;
        }
        __syncthreads();
        for (int ii = 0; ii < 4; ++ii)
            for (int jj = 0; jj < 4; ++jj)
                Xs[(64 * p + 4 * tb + ii) * 68 + 4 * tj + jj] = acc2[ii][jj];
    }
    // ---- backward: U (incl diag) ----
    for (int p = 3; p >= 0; --p) {
        float acc[4][4] = {{0.f}};
        for (int q = p + 1; q < 4; ++q) {
            __syncthreads();
            for (int e = tid; e < 4096; e += 256) {
                int r = e >> 6, c = e & 63;
                Lt[c * 68 + r] = M[(64 * p + r) * 256 + 64 * q + c];  // Lt[k][i]=U_pq[i][k]
            }
            __syncthreads();
            for (int kl = 0; kl < 64; ++kl) {
                float4 a4 = *(const float4*)&Lt[kl * 68 + 4 * tb];
                float4 b4 = *(const float4*)&Xs[(64 * q + kl) * 68 + 4 * tj];
                acc[0][0] += a4.x * b4.x; acc[0][1] += a4.x * b4.y; acc[0][2] += a4.x * b4.z; acc[0][3] += a4.x * b4.w;
                acc[1][0] += a4.y * b4.x; acc[1][1] += a4.y * b4.y; acc[1][2] += a4.y * b4.z; acc[1][3] += a4.y * b4.w;
                acc[2][0] += a4.z * b4.x; acc[2][1] += a4.z * b4.y; acc[2][2] += a4.z * b4.z; acc[2][3] += a4.z * b4.w;
                acc[3][0] += a4.w * b4.x; acc[3][1] += a4.w * b4.y; acc[3][2] += a4.w * b4.z; acc[3][3] += a4.w * b4.w;
            }
        }
        __syncthreads();
        for (int ii = 0; ii < 4; ++ii)
            for (int jj = 0; jj < 4; ++jj)
                Xs[(64 * p + 4 * tb + ii) * 68 + 4 * tj + jj] -= acc[ii][jj];
        __syncthreads();
        for (int e = tid; e < 4096; e += 256) {
            int r = e >> 6, c = e & 63;
            Lt[c * 68 + r] = Uinv[p * 4096 + r * 64 + c];
        }
        __syncthreads();
        float acc2[4][4] = {{0.f}};
        for (int kl = 0; kl < 64; ++kl) {
            float4 a4 = *(const float4*)&Lt[kl * 68 + 4 * tb];
            float4 b4 = *(const float4*)&Xs[(64 * p + kl) * 68 + 4 * tj];
            acc2[0][0] += a4.x * b4.x; acc2[0][1] += a4.x * b4.y; acc2[0][2] += a4.x * b4.z; acc2[0][3] += a4.x * b4.w;
            acc2[1][0] += a4.y * b4.x; acc2[1][1] += a4.y * b4.y; acc2[1][2] += a4.y * b4.z; acc2[1][3] += a4.y * b4.w;
            acc2[2][0] += a4.z * b4.x; acc2[2][1] += a4.z * b4.y; acc2[2][2] += a4.z * b4.z; acc2[2][3] += a4.z * b4.w;
            acc2[3][0] += a4.w * b4.x; acc2[3][1] += a4.w * b4.y; acc2[3][2] += a4.w * b4.z; acc2[3][3] += a4.w * b4.w;
        }
        __syncthreads();
        for (int ii = 0; ii < 4; ++ii)
            for (int jj = 0; jj < 4; ++jj)
                Xs[(64 * p + 4 * tb + ii) * 68 + 4 * tj + jj] = acc2[ii][jj];
    }
    __syncthreads();
    for (int e = tid; e < 256 * 64; e += 256) {
        int row = e >> 6, cc = e & 63;
        if (cc < ncol) X[row * ld + cbase + cc] = Xs[row * 68 + cc];
    }
}

// ======================= SDA updates =======================
__global__ void k_upd1(const float* __restrict__ F, const float* __restrict__ H,
                       const float* __restrict__ XF, const float* __restrict__ XG,
                       const float* __restrict__ z, const float* __restrict__ h,
                       float* __restrict__ Fn, float* __restrict__ HXF,
                       float* __restrict__ P, float* __restrict__ wv,
                       float* __restrict__ av) {
    int b = blockIdx.x;
    if (b < 16)       mm_tile(F, XF, nullptr, Fn,  0, 0, 0, b >> 2, b & 3);
    else if (b < 32)  mm_tile(H, XF, nullptr, HXF, 0, 0, 0, (b - 16) >> 2, (b - 16) & 3);
    else if (b < 48)  mm_tile(F, XG, nullptr, P,   0, 0, 0, (b - 32) >> 2, (b - 32) & 3);
    else if (b == 48) {
        int i = threadIdx.x;
        float acc = h[i];
        for (int j = 0; j < 256; ++j) acc += H[j * 256 + i] * z[j];  // H symmetric
        wv[i] = acc;
    } else {
        int i = threadIdx.x;
        float acc = 0.f;
        for (int j = 0; j < 256; ++j) acc += F[i * 256 + j] * z[j];
        av[i] = acc;
    }
}

__global__ void k_upd2(const float* __restrict__ F, const float* __restrict__ HXF,
                       const float* __restrict__ P, const float* __restrict__ wv,
                       const float* __restrict__ av, float* __restrict__ H,
                       float* __restrict__ G, float* __restrict__ h,
                       float* __restrict__ a) {
    int b = blockIdx.x;
    if (b < 16)       mm_tile(F, HXF, H, H, 1, 0, 0, b >> 2, b & 3);
    else if (b < 32)  mm_tile(P, F,   G, G, 0, 1, 0, (b - 16) >> 2, (b - 16) & 3);
    else {
        int i = threadIdx.x;
        float acc = h[i];
        for (int pp = 0; pp < 256; ++pp) acc += F[pp * 256 + i] * wv[pp];
        h[i] = acc;
        a[i] += av[i];
    }
}

// ======================= final gains =======================
__global__ void k_btv(const float* __restrict__ B, const float* __restrict__ V,
                      const float* __restrict__ v, float* __restrict__ BtV,
                      float* __restrict__ btv) {
    if (blockIdx.x < 64) {
        int idx = blockIdx.x * 256 + threadIdx.x;
        int i = idx >> 8, q = idx & 255;
        float acc = 0.f;
        for (int p2 = 0; p2 < 256; ++p2) acc += B[p2 * 64 + i] * V[p2 * 256 + q];
        BtV[idx] = acc;
    } else if (threadIdx.x < 64) {
        int i = threadIdx.x;
        float acc = 0.f;
        for (int p2 = 0; p2 < 256; ++p2) acc += B[p2 * 64 + i] * v[p2];
        btv[i] = acc;
    }
}

__global__ void k_SVuu(const float* __restrict__ A, const float* __restrict__ B,
                       const float* __restrict__ rl, const float* __restrict__ BtV,
                       float* __restrict__ S, float* __restrict__ Vuu) {
    int bx = blockIdx.x;
    if (bx < 64) {
        int idx = bx * 256 + threadIdx.x;
        int i = idx >> 8, q = idx & 255;
        float acc = 0.f;
        for (int p2 = 0; p2 < 256; ++p2) acc += BtV[i * 256 + p2] * A[p2 * 256 + q];
        S[idx] = acc;
    } else {
        int tdx = (bx - 64) * 256 + threadIdx.x;
        int i = tdx >> 6, j = tdx & 63;
        float acc = (i == j) ? expf(rl[i]) : 0.f;
        for (int p2 = 0; p2 < 256; ++p2) acc += BtV[i * 256 + p2] * B[p2 * 64 + j];
        Vuu[tdx] = acc;
    }
}

// 64x64 SPD Cholesky, 1 WG
__global__ void k_chol(const float* __restrict__ Vuu, float* __restrict__ L) {
    __shared__ float Msh[64 * 64];
    int tid = threadIdx.x;
    for (int e = tid; e < 4096; e += 256) Msh[e] = Vuu[e];
    __syncthreads();
    int i = tid & 63, c = tid >> 6;
    for (int j = 0; j < 64; ++j) {
        if (tid == 0) Msh[j * 64 + j] = sqrtf(Msh[j * 64 + j]);
        __syncthreads();
        float d = Msh[j * 64 + j];
        if (c == 0 && i > j) Msh[i * 64 + j] /= d;
        __syncthreads();
        if (i > j) {
            float lij = Msh[i * 64 + j];
            for (int k = j + 1 + c; k <= i; k += 4)
                Msh[i * 64 + k] -= lij * Msh[k * 64 + j];
        }
        __syncthreads();
    }
    for (int e = tid; e < 4096; e += 256) {
        int r = e >> 6, k = e & 63;
        L[e] = (k <= r) ? Msh[e] : 0.f;
    }
}

// K0 = Vuu^-1 S, k0 = Vuu^-1 btv (fwd+bwd via wave shuffles)
__global__ void k_solveK(const float* __restrict__ L, const float* __restrict__ S,
                         const float* __restrict__ btv,
                         float* __restrict__ K0, float* __restrict__ k0) {
    int w = (blockIdx.x * 256 + threadIdx.x) >> 6;
    int lane = threadIdx.x & 63;
    if (w >= 257) return;
    float x = (w < 256) ? S[lane * 256 + w] : btv[lane];
    for (int a = 0; a < 64; ++a) {
        float val = (lane < a) ? L[a * 64 + lane] * x : 0.f;
        for (int o = 32; o > 0; o >>= 1) val += __shfl_xor(val, o, 64);
        float xa = (__shfl(x, a, 64) - val) / L[a * 64 + a];
        if (lane == a) x = xa;
    }
    for (int a = 63; a >= 0; --a) {
        float val = (lane > a) ? L[lane * 64 + a] * x : 0.f;
        for (int o = 32; o > 0; o >>= 1) val += __shfl_xor(val, o, 64);
        float xa = (__shfl(x, a, 64) - val) / L[a * 64 + a];
        if (lane == a) x = xa;
    }
    if (w < 256) K0[lane * 256 + w] = x;
    else k0[lane] = x;
}

// u = clip(-g0 @ K0^T + k0)
__global__ __launch_bounds__(256) void k_gemm(const float* __restrict__ g0,
                                              const float* __restrict__ K0,
                                              const float* __restrict__ k0,
                                              float* __restrict__ out) {
    __shared__ __align__(16) float g0t[64 * 68];
    __shared__ __align__(16) float kt[64 * 68];
    int tid = threadIdx.x;
    int base = blockIdx.x * 64;
    int tb = tid >> 4;
    int tj = tid & 15;
    float acc[4][4] = {{0.f}};
    for (int kc = 0; kc < 4; ++kc) {
        __syncthreads();
        for (int e = tid; e < 4096; e += 256) {
            int r = e >> 6, kl = e & 63;
            g0t[kl * 68 + r] = g0[(base + r) * 256 + kc * 64 + kl];
        }
        for (int e = tid; e < 4096; e += 256) {
            int j = e >> 6, kl = e & 63;
            kt[kl * 68 + j] = K0[j * 256 + kc * 64 + kl];
        }
        __syncthreads();
        for (int kl = 0; kl < 64; ++kl) {
            float4 g = *(const float4*)&g0t[kl * 68 + 4 * tb];
            float4 kv = *(const float4*)&kt[kl * 68 + 4 * tj];
            acc[0][0] += g.x * kv.x; acc[0][1] += g.x * kv.y; acc[0][2] += g.x * kv.z; acc[0][3] += g.x * kv.w;
            acc[1][0] += g.y * kv.x; acc[1][1] += g.y * kv.y; acc[1][2] += g.y * kv.z; acc[1][3] += g.y * kv.w;
            acc[2][0] += g.z * kv.x; acc[2][1] += g.z * kv.y; acc[2][2] += g.z * kv.z; acc[2][3] += g.z * kv.w;
            acc[3][0] += g.w * kv.x; acc[3][1] += g.w * kv.y; acc[3][2] += g.w * kv.z; acc[3][3] += g.w * kv.w;
        }
    }
    float c0 = k0[4 * tj + 0], c1 = k0[4 * tj + 1], c2 = k0[4 * tj + 2], c3 = k0[4 * tj + 3];
    for (int i = 0; i < 4; ++i) {
        float4 o;
        o.x = fminf(1.0f, fmaxf(-1.0f, c0 - acc[i][0]));
        o.y = fminf(1.0f, fmaxf(-1.0f, c1 - acc[i][1]));
        o.z = fminf(1.0f, fmaxf(-1.0f, c2 - acc[i][2]));
        o.w = fminf(1.0f, fmaxf(-1.0f, c3 - acc[i][3]));
        *(float4*)&out[(base + 4 * tb + i) * 64 + 4 * tj] = o;
    }
}

extern "C" void kernel_launch(void* const* d_in, const int* in_sizes, int n_in,
                              void* d_out, int out_size, void* d_ws, size_t ws_size,
                              hipStream_t stream) {
    const float* g0 = (const float*)d_in[0];
    const float* A  = (const float*)d_in[1];
    const float* B  = (const float*)d_in[2];
    const float* ql = (const float*)d_in[3];
    const float* rl = (const float*)d_in[4];
    const float* gg = (const float*)d_in[5];
    // d_in[6] = T == 256, hardcoded (log2 T = 8 doublings).

    float* ws = (float*)d_ws;
    float* G    = ws;             // 65536
    float* H    = G    + 65536;
    float* F0   = H    + 65536;
    float* F1   = F0   + 65536;
    float* M    = F1   + 65536;
    float* XF   = M    + 65536;
    float* XG   = XF   + 65536;
    float* HXF  = XG   + 65536;
    float* P    = HXF  + 65536;
    float* Linv = P    + 65536;   // 16384 (4 x 64x64)
    float* Uinv = Linv + 16384;   // 16384
    float* BtV  = Uinv + 16384;   // 16384
    float* S    = BtV  + 16384;   // 16384
    float* K0   = S    + 16384;   // 16384
    float* Vuu  = K0   + 16384;   // 4096
    float* L64  = Vuu  + 4096;    // 4096
    float* a    = L64  + 4096;    // 256
    float* h    = a    + 256;     // 256
    float* t    = h    + 256;     // 256
    float* z    = t    + 256;     // 256
    float* wv   = z    + 256;     // 256
    float* av   = wv   + 256;     // 256
    float* rinv = av   + 256;     // 64
    float* btv  = rinv + 64;      // 64
    float* k0v  = btv  + 64;      // 64

    k_init<<<256, 256, 0, stream>>>(ql, rl, gg, A, H, F0, a, h, rinv);
    k_initG<<<256, 256, 0, stream>>>(B, rinv, G);

    float* Fc = F0; float* Fn = F1;
    for (int it = 0; it < 8; ++it) {
        k_formMt<<<17, 256, 0, stream>>>(G, H, a, h, M, t);
        for (int p = 0; p < 4; ++p) {
            k_lu_panel<<<1, 256, 0, stream>>>(M, Linv, Uinv, p);
            if (p < 3) {
                k_trsm2<<<3 - p, 256, 0, stream>>>(M, Linv, p);
                k_lu_trail<<<(3 - p) * (3 - p), 256, 0, stream>>>(M, p);
            }
        }
        k_solve_all<<<9, 256, 0, stream>>>(M, Linv, Uinv, Fc, G, t, XF, XG, z);
        k_upd1<<<50, 256, 0, stream>>>(Fc, H, XF, XG, z, h, Fn, HXF, P, wv, av);
        k_upd2<<<33, 256, 0, stream>>>(Fc, HXF, P, wv, av, H, G, h, a);
        float* tmp = Fc; Fc = Fn; Fn = tmp;
    }

    // gains from V = H_8, v = h_8
    k_btv<<<65, 256, 0, stream>>>(B, H, h, BtV, btv);
    k_SVuu<<<80, 256, 0, stream>>>(A, B, rl, BtV, S, Vuu);
    k_chol<<<1, 256, 0, stream>>>(Vuu, L64);
    k_solveK<<<65, 256, 0, stream>>>(L64, S, btv, K0, k0v);
    k_gemm<<<NB / 64, 256, 0, stream>>>(g0, K0, k0v, (float*)d_out);
}